// Round 13
// baseline (74.450 us; speedup 1.0000x reference)
//
#include <hip/hip_runtime.h>

#define NFEAT 38

typedef __attribute__((ext_vector_type(8))) short bf16x8;
typedef __attribute__((ext_vector_type(4))) float f32x4;
typedef __attribute__((ext_vector_type(2))) float f32x2;
typedef __attribute__((ext_vector_type(4))) unsigned int u32x4;

// bf16 table row bases (rows of 256 cols, 512 B)
#define R_SP   0      // 512 fused species rows
#define R_AB   512    // 128 fused ability rows
#define R_IT   640    // 256 fused item rows
#define R_T1   896    // 404: (f3,f4,f5)
#define R_T2   1300   // 128: (f6,f11,f12), hp folded
#define R_T3   1428   // 24 : (f7,f8)
#define R_T4   1452   // 32 : (f9,f10)
#define R_T5   1484   // 64 : (f13,f14,f15)
#define R_T6   1548   // 169: (f16,f17)
#define R_T7   1717   // 169: (f18,f19)
#define R_T8   1886   // 169: (f20,f21)
#define R_T9   2055   // 13 : f22
#define R_ACT  2068   // 512: actions_emb
#define NROWS  2580   // 1,320,960 B  (fits one XCD L2)

// k_prep block layout (1024 threads each)
#define B_FUSED  0     // 224: fused sp/ab/it rows
#define B_WMLP   224   // 64 : fragment-ordered bf16 mlp_w
#define B_WBITS  288   // 48 : fragment-ordered bf16 bits-weights (192x256, padded)
#define B_MERGED 336   // 421: merged one-hot/boost/action rows
#define B_IDXS   757   // 64 : per-entity packed ridx (16 rows + 6 bitwords)
#define NB_PREP  821

__device__ __forceinline__ unsigned short f2bf(float f) {
    unsigned int u = __float_as_uint(f);
    u += 0x7fffu + ((u >> 16) & 1u);   // round-to-nearest-even
    return (unsigned short)(u >> 16);
}

// single-inst packed f32->bf16 (RTNE), low = lo, high = hi
__device__ __forceinline__ unsigned int cvt_pk_bf16(float lo, float hi) {
    unsigned int r;
    asm("v_cvt_pk_bf16_f32 %0, %1, %2" : "=v"(r) : "v"(lo), "v"(hi));
    return r;
}

// ---------------------------------------------------------------------------
// K0: all prep
// ---------------------------------------------------------------------------
__global__ __launch_bounds__(1024) void k_prep(
    const float* __restrict__ sp_tbl, const float* __restrict__ ab_tbl,
    const float* __restrict__ it_tbl, const float* __restrict__ sp_emb,
    const float* __restrict__ ab_emb, const float* __restrict__ it_emb,
    const float* __restrict__ act_emb, const float* __restrict__ agg_w,
    const float* __restrict__ agg_b,  const float* __restrict__ mlp_w,
    const int* __restrict__ ent,
    unsigned short* __restrict__ tbl, unsigned short* __restrict__ wfrag,
    unsigned short* __restrict__ wbits, unsigned int* __restrict__ ridx)
{
    __shared__ float rowbuf[4 * 512];
    __shared__ float part[4][4][256];
    int blk = blockIdx.x, t = threadIdx.x, c = t & 255;
#define W(x) agg_w[(size_t)(x) * 256 + c]

    if (blk < B_WMLP) {
        // ---- fused species/ability/item rows: 4 rows/block, K split 4 ways ----
        int r0 = blk << 2;
        const float* src; const float* emb; int len, wbase; bool add_b;
        if (r0 < 512)      { src = sp_tbl + (size_t)r0 * 512;           emb = sp_emb + (size_t)r0 * 256;           len = 512; wbase = 0;   add_b = true;  }
        else if (r0 < 640) { int q = r0 - 512; src = ab_tbl + (size_t)q * 128; emb = ab_emb + (size_t)q * 256; len = 128; wbase = 512; add_b = false; }
        else               { int q = r0 - 640; src = it_tbl + (size_t)q * 256; emb = it_emb + (size_t)q * 256; len = 256; wbase = 640; add_b = false; }
        int tot = len << 2;
        for (int i = t; i < tot; i += 1024) rowbuf[i] = src[i];
        __syncthreads();
        int kq   = t >> 8;
        int len4 = len >> 2;
        int kbeg = kq * len4, kend = kbeg + len4;
        float a0 = 0.f, a1 = 0.f, a2 = 0.f, a3 = 0.f;
        #pragma unroll 4
        for (int k = kbeg; k < kend; ++k) {
            float w = W(wbase + k);
            a0 += rowbuf[k] * w;
            a1 += rowbuf[len + k] * w;
            a2 += rowbuf[2 * len + k] * w;
            a3 += rowbuf[3 * len + k] * w;
        }
        part[0][kq][c] = a0; part[1][kq][c] = a1;
        part[2][kq][c] = a2; part[3][kq][c] = a3;
        __syncthreads();
        int row = t >> 8;
        float s = part[row][0][c] + part[row][1][c] + part[row][2][c] + part[row][3][c]
                + emb[row * 256 + c] + (add_b ? agg_b[c] : 0.f);
        tbl[(size_t)(r0 + row) * 256 + c] = f2bf(s);
        return;
    }
    if (blk < B_WBITS) {
        // ---- fragment-ordered bf16 mlp_w ----
        int idx = ((blk - B_WMLP) << 10) + t;   // 0..65535
        int j   = idx & 7;
        int fl  = (idx >> 3) & 63;
        int k0g = (idx >> 9) & 7;
        int nt  = idx >> 12;
        int k   = k0g * 32 + (fl >> 4) * 8 + j;
        int col = nt * 16 + (fl & 15);
        wfrag[idx] = f2bf(mlp_w[(size_t)k * 256 + col]);
        return;
    }
    if (blk < B_MERGED) {
        // ---- fragment-ordered bf16 bits-weights (rows 1171..1346 of agg_w) ----
        int idx = ((blk - B_WBITS) << 10) + t;  // 0..49151
        int j   = idx & 7;
        int ln  = (idx >> 3) & 63;
        int r2  = idx >> 9;                     // 0..95
        int kt  = r2 % 6;
        int nt  = r2 / 6;
        int k   = kt * 32 + ((ln >> 4) << 3) + j;
        int col = (nt << 4) + (ln & 15);
        float v = (k < 176) ? agg_w[(size_t)(1171 + k) * 256 + col] : 0.f;
        wbits[idx] = f2bf(v);
        return;
    }
    if (blk < B_IDXS) {
        // ---- merged category rows: 4 rows per block ----
        int r = ((blk - B_MERGED) << 2) + (t >> 8);   // 0..1683
        int row; float acc;
        if (r < 404)       { int f3 = r >> 2, f4 = (r >> 1) & 1, f5 = r & 1;
                             acc = W(896 + f3) + W(997 + f4) + W(999 + f5); row = R_T1 + r; }
        else if (r < 532)  { int i = r - 404; int f6 = i >> 2, f11 = (i >> 1) & 1, f12 = i & 1;
                             acc = W(1001 + f6) + (float)f6 * (1.f / 31.f) * W(1347)
                                 + W(1062 + f11) + W(1064 + f12); row = R_T2 + i; }
        else if (r < 556)  { int i = r - 532; acc = W(1033 + (i >> 3)) + W(1036 + (i & 7)); row = R_T3 + i; }
        else if (r < 588)  { int i = r - 556; acc = W(1044 + (i >> 1)) + W(1060 + (i & 1)); row = R_T4 + i; }
        else if (r < 652)  { int i = r - 588; acc = W(1066 + (i >> 3)) + W(1074 + ((i >> 1) & 3)) + W(1078 + (i & 1)); row = R_T5 + i; }
        else if (r < 821)  { int i = r - 652; acc = W(1080 + i / 13) + W(1093 + i % 13); row = R_T6 + i; }
        else if (r < 990)  { int i = r - 821; acc = W(1106 + i / 13) + W(1119 + i % 13); row = R_T7 + i; }
        else if (r < 1159) { int i = r - 990; acc = W(1132 + i / 13) + W(1145 + i % 13); row = R_T8 + i; }
        else if (r < 1172) { int i = r - 1159; acc = W(1158 + i); row = R_T9 + i; }
        else               { int i = r - 1172; acc = act_emb[(size_t)i * 256 + c]; row = R_ACT + i; }
        tbl[(size_t)row * 256 + c] = f2bf(acc);
        return;
    }
    {
        // ---- per-entity packed ridx: 8 row-pairs + 6 bitwords + pad = 64 B ----
        int e = ((blk - B_IDXS) << 10) + t;
        size_t bb = (size_t)e * (NFEAT * 4);
        const uint4* wp = reinterpret_cast<const uint4*>(
            reinterpret_cast<const char*>(ent) + (bb & ~(size_t)15));
        uint4 q0 = wp[0], q1 = wp[1], q2 = wp[2], q3 = wp[3], q4 = wp[4];
        uint4 q5 = wp[5], q6 = wp[6], q7 = wp[7], q8 = wp[8], q9 = wp[9];
        unsigned int v[40] = {q0.x,q0.y,q0.z,q0.w, q1.x,q1.y,q1.z,q1.w,
                              q2.x,q2.y,q2.z,q2.w, q3.x,q3.y,q3.z,q3.w,
                              q4.x,q4.y,q4.z,q4.w, q5.x,q5.y,q5.z,q5.w,
                              q6.x,q6.y,q6.z,q6.w, q7.x,q7.y,q7.z,q7.w,
                              q8.x,q8.y,q8.z,q8.w, q9.x,q9.y,q9.z,q9.w};
        int f[NFEAT];
        if (e & 1) {
            #pragma unroll
            for (int i = 0; i < NFEAT; ++i) f[i] = (int)v[i + 2];
        } else {
            #pragma unroll
            for (int i = 0; i < NFEAT; ++i) f[i] = (int)v[i];
        }
        int rw[16];
        rw[0]  = f[0];
        rw[1]  = R_AB + f[1];
        rw[2]  = R_IT + f[2];
        rw[3]  = R_T1 + f[3] * 4 + f[4] * 2 + f[5];
        rw[4]  = R_T2 + f[6] * 4 + f[11] * 2 + f[12];
        rw[5]  = R_T3 + f[7] * 8 + f[8];
        rw[6]  = R_T4 + f[9] * 2 + f[10];
        rw[7]  = R_T5 + f[13] * 8 + f[14] * 2 + f[15];
        rw[8]  = R_T6 + f[16] * 13 + f[17];
        rw[9]  = R_T7 + f[18] * 13 + f[19];
        rw[10] = R_T8 + f[20] * 13 + f[21];
        rw[11] = R_T9 + f[22];
        rw[12] = R_ACT + f[34];
        rw[13] = R_ACT + f[35];
        rw[14] = R_ACT + f[36];
        rw[15] = R_ACT + f[37];
        unsigned int p[16];
        #pragma unroll
        for (int i = 0; i < 8; ++i)
            p[i] = (unsigned int)rw[2 * i] | ((unsigned int)rw[2 * i + 1] << 16);
        #pragma unroll
        for (int i = 0; i < 5; ++i)
            p[8 + i] = (unsigned int)(f[23 + 2 * i] & 0xffff) | ((unsigned int)f[24 + 2 * i] << 16);
        p[13] = (unsigned int)(f[33] & 0xffff);
        p[14] = 0; p[15] = 0;
        uint4* dst = reinterpret_cast<uint4*>(ridx + (size_t)e * 16);
        dst[0] = make_uint4(p[0], p[1], p[2], p[3]);
        dst[1] = make_uint4(p[4], p[5], p[6], p[7]);
        dst[2] = make_uint4(p[8], p[9], p[10], p[11]);
        dst[3] = make_uint4(p[12], p[13], p[14], p[15]);
    }
#undef W
}

// ---------------------------------------------------------------------------
// K1: fused encode + mlp.  Block = 512 threads (8 waves), 64 entities.
//  A1: wave w encodes entities w*8..w*8+7.  Per entity: 16 single-row
//      global_load_dwordx2 (scalar saddr + constant lane voffset), ALL 64
//      lanes on the same row (lane owns 4 cols), batch-issued; packed-f32
//      accumulate; cvt_pk_bf16 -> xw (XOR-swizzled 16B units).  No shuffles.
//  A2: bits contribution via MFMA (A = expanded 0/1 bits, B = static wbits
//      fragments); in-place RMW: x = bf16(relu(f32(x) + D)).
//  B : mlp MFMA (A from xw, B from wfrag), bias + species mask, store.
// ---------------------------------------------------------------------------
__global__ __launch_bounds__(512, 8) void k_fused_em(
    const unsigned int* __restrict__ ridx, const unsigned short* __restrict__ tbl,
    const unsigned short* __restrict__ wfrag, const unsigned short* __restrict__ wbits,
    const float* __restrict__ mlp_b, float* __restrict__ out)
{
    __shared__ unsigned short xw[64 * 256];   // 32,768 B
    __shared__ unsigned int bitw[64 * 6];     // 1,536 B
    __shared__ unsigned char smask[64];
    int t    = threadIdx.x;
    int w    = t >> 6;
    int lane = t & 63;
    int wu   = __builtin_amdgcn_readfirstlane(w);
    int eb   = blockIdx.x << 6;
    const char* tb = reinterpret_cast<const char*>(tbl);
    char* xb = reinterpret_cast<char*>(xw);

    // stage bitwords + species mask
    if (t < 384) {
        int e = t / 6, k = t - e * 6;
        bitw[t] = ridx[(size_t)(eb + e) * 16 + 8 + k];
    }
    if (t < 64) smask[t] = ((ridx[(size_t)(eb + t) * 16] & 0xffffu) < 2u) ? 1 : 0;

    // ---------------- A1: gather-encode 8 entities -> bf16 in xw ------------
    {
        int cb8 = lane << 3;                  // byte offset of lane's 4 cols
        for (int i = 0; i < 8; ++i) {
            int el = (wu << 3) + i;
            const unsigned int* rq = ridx + (size_t)(eb + el) * 16;  // uniform
            uint2 v[16];
            #pragma unroll
            for (int j = 0; j < 16; ++j) {
                unsigned int pj  = rq[j >> 1];                       // scalar
                unsigned int row = (j & 1) ? (pj >> 16) : (pj & 0xffffu);
                v[j] = *reinterpret_cast<const uint2*>(tb + ((size_t)row << 9) + cb8);
            }
            f32x2 aA = (f32x2){0.f, 0.f};     // cols {c, c+2}
            f32x2 aB = (f32x2){0.f, 0.f};     // cols {c+1, c+3}
            #pragma unroll
            for (int j = 0; j < 16; ++j) {
                aA += (f32x2){__uint_as_float(v[j].x << 16),         __uint_as_float(v[j].y << 16)};
                aB += (f32x2){__uint_as_float(v[j].x & 0xffff0000u), __uint_as_float(v[j].y & 0xffff0000u)};
            }
            unsigned int o0 = cvt_pk_bf16(aA[0], aB[0]);   // cols c, c+1
            unsigned int o1 = cvt_pk_bf16(aA[1], aB[1]);   // cols c+2, c+3
            int up = (lane >> 1) ^ (el & 7);
            *reinterpret_cast<uint2*>(xb + (el << 9) + (up << 4) + ((lane & 1) << 3)) =
                make_uint2(o0, o1);
        }
    }
    __syncthreads();

    // ---------------- A2: bits via MFMA + in-place relu RMW -----------------
    int rc  = lane & 15;
    int kg  = lane >> 4;
    int nt0 = wu << 1;
    int c0  = wu << 5;

    f32x4 D0[4], D1[4];
    #pragma unroll
    for (int mt = 0; mt < 4; ++mt) { D0[mt] = (f32x4){0.f,0.f,0.f,0.f}; D1[mt] = (f32x4){0.f,0.f,0.f,0.f}; }

    #pragma unroll
    for (int kt = 0; kt < 6; ++kt) {
        bf16x8 b0 = *reinterpret_cast<const bf16x8*>(wbits + (((size_t)(nt0 * 6 + kt)) << 9) + (lane << 3));
        bf16x8 b1 = *reinterpret_cast<const bf16x8*>(wbits + (((size_t)((nt0 + 1) * 6 + kt)) << 9) + (lane << 3));
        #pragma unroll
        for (int mt = 0; mt < 4; ++mt) {
            unsigned int wb = bitw[((mt << 4) + rc) * 6 + kt];
            unsigned int bs = wb >> (kg << 3);
            unsigned int e0 = ((bs & 1u)   ? 0x3F80u : 0u) | ((bs & 2u)   ? 0x3F800000u : 0u);
            unsigned int e1 = ((bs & 4u)   ? 0x3F80u : 0u) | ((bs & 8u)   ? 0x3F800000u : 0u);
            unsigned int e2 = ((bs & 16u)  ? 0x3F80u : 0u) | ((bs & 32u)  ? 0x3F800000u : 0u);
            unsigned int e3 = ((bs & 64u)  ? 0x3F80u : 0u) | ((bs & 128u) ? 0x3F800000u : 0u);
            bf16x8 afr = __builtin_bit_cast(bf16x8, (u32x4){e0, e1, e2, e3});
            D0[mt] = __builtin_amdgcn_mfma_f32_16x16x32_bf16(afr, b0, D0[mt], 0, 0, 0);
            D1[mt] = __builtin_amdgcn_mfma_f32_16x16x32_bf16(afr, b1, D1[mt], 0, 0, 0);
        }
    }

    #pragma unroll
    for (int mt = 0; mt < 4; ++mt) {
        #pragma unroll
        for (int j = 0; j < 4; ++j) {
            int row  = (mt << 4) + (kg << 2) + j;
            int colA = c0 + rc;
            int colB = colA + 16;
            int uA = (colA >> 3) ^ (row & 7);
            int uB = (colB >> 3) ^ (row & 7);
            unsigned short* pA = reinterpret_cast<unsigned short*>(
                xb + (row << 9) + (uA << 4) + ((colA & 7) << 1));
            unsigned short* pB = reinterpret_cast<unsigned short*>(
                xb + (row << 9) + (uB << 4) + ((colB & 7) << 1));
            float xA = __uint_as_float((unsigned int)(*pA) << 16) + D0[mt][j];
            float xB = __uint_as_float((unsigned int)(*pB) << 16) + D1[mt][j];
            *pA = (unsigned short)cvt_pk_bf16(fmaxf(xA, 0.f), 0.f);
            *pB = (unsigned short)cvt_pk_bf16(fmaxf(xB, 0.f), 0.f);
        }
    }
    __syncthreads();

    // ---------------- B: mlp MFMA, 64 rows x 32 cols per wave ---------------
    f32x4 acc0[4], acc1[4];
    #pragma unroll
    for (int mt = 0; mt < 4; ++mt) {
        acc0[mt] = (f32x4){0.f,0.f,0.f,0.f};
        acc1[mt] = (f32x4){0.f,0.f,0.f,0.f};
    }

    #pragma unroll
    for (int k0g = 0; k0g < 8; ++k0g) {
        bf16x8 b0 = *reinterpret_cast<const bf16x8*>(
            wfrag + (((size_t)(nt0 * 8 + k0g)) << 9) + (lane << 3));
        bf16x8 b1 = *reinterpret_cast<const bf16x8*>(
            wfrag + (((size_t)((nt0 + 1) * 8 + k0g)) << 9) + (lane << 3));
        int up = ((k0g << 2) + kg) ^ (rc & 7);
        #pragma unroll
        for (int mt = 0; mt < 4; ++mt) {
            int r = (mt << 4) + rc;
            bf16x8 a = *reinterpret_cast<const bf16x8*>(xb + (r << 9) + (up << 4));
            acc0[mt] = __builtin_amdgcn_mfma_f32_16x16x32_bf16(a, b0, acc0[mt], 0, 0, 0);
            acc1[mt] = __builtin_amdgcn_mfma_f32_16x16x32_bf16(a, b1, acc1[mt], 0, 0, 0);
        }
    }

    float bias0 = mlp_b[c0 + rc];
    float bias1 = mlp_b[c0 + 16 + rc];
    #pragma unroll
    for (int mt = 0; mt < 4; ++mt) {
        unsigned int mw = *reinterpret_cast<const unsigned int*>(&smask[(mt << 4) + (kg << 2)]);
        #pragma unroll
        for (int j = 0; j < 4; ++j) {
            int row = eb + (mt << 4) + (kg << 2) + j;
            bool m = (mw >> (8 * j)) & 1u;
            out[(size_t)row * 256 + c0 + rc]      = m ? 0.f : (acc0[mt][j] + bias0);
            out[(size_t)row * 256 + c0 + 16 + rc] = m ? 0.f : (acc1[mt][j] + bias1);
        }
    }
}

// ---------------------------------------------------------------------------
extern "C" void kernel_launch(void* const* d_in, const int* in_sizes, int n_in,
                              void* d_out, int out_size, void* d_ws, size_t ws_size,
                              hipStream_t stream)
{
    const int*   ent     = (const int*)d_in[0];
    const float* sp_tbl  = (const float*)d_in[1];
    const float* ab_tbl  = (const float*)d_in[2];
    const float* it_tbl  = (const float*)d_in[3];
    const float* sp_emb  = (const float*)d_in[4];
    const float* ab_emb  = (const float*)d_in[5];
    const float* it_emb  = (const float*)d_in[6];
    const float* act_emb = (const float*)d_in[7];
    const float* agg_w   = (const float*)d_in[8];
    const float* agg_b   = (const float*)d_in[9];
    const float* mlp_w   = (const float*)d_in[10];
    const float* mlp_b   = (const float*)d_in[11];
    float* out = (float*)d_out;

    char* ws = (char*)d_ws;
    unsigned short* tbl   = (unsigned short*)(ws);               // 2580*512   = 1,320,960 B
    unsigned short* wfrag = (unsigned short*)(ws + 1320960);     //   131,072 B
    unsigned short* wbits = (unsigned short*)(ws + 1452032);     //    98,304 B
    unsigned int*   ridx  = (unsigned int*)  (ws + 1550336);     // 65536*64   = 4,194,304 B

    k_prep    <<<dim3(NB_PREP), dim3(1024), 0, stream>>>(sp_tbl, ab_tbl, it_tbl,
                                                         sp_emb, ab_emb, it_emb,
                                                         act_emb, agg_w, agg_b, mlp_w,
                                                         ent, tbl, wfrag, wbits, ridx);
    k_fused_em<<<dim3(1024),    dim3(512),  0, stream>>>(ridx, tbl, wfrag, wbits, mlp_b, out);
}

// Round 15
// 66.835 us; speedup vs baseline: 1.1139x; 1.1139x over previous
//
#include <hip/hip_runtime.h>

#define NFEAT 38

typedef __attribute__((ext_vector_type(8))) short bf16x8;
typedef __attribute__((ext_vector_type(4))) float f32x4;
typedef __attribute__((ext_vector_type(2))) float f32x2;
typedef __attribute__((ext_vector_type(4))) unsigned int u32x4;

// bf16 table row bases (rows of 256 cols, 512 B)
#define R_SP   0      // 512 fused species rows
#define R_AB   512    // 128 fused ability rows
#define R_IT   640    // 256 fused item rows
#define R_T1   896    // 404: (f3,f4,f5)
#define R_T2   1300   // 128: (f6,f11,f12), hp folded
#define R_T3   1428   // 24 : (f7,f8)
#define R_T4   1452   // 32 : (f9,f10)
#define R_T5   1484   // 64 : (f13,f14,f15)
#define R_T6   1548   // 169: (f16,f17)
#define R_T7   1717   // 169: (f18,f19)
#define R_T8   1886   // 169: (f20,f21)
#define R_T9   2055   // 13 : f22
#define R_ACT  2068   // 512: actions_emb
#define NROWS  2580   // 1,320,960 B  (fits one XCD L2)

// k_prep block layout (1024 threads each)
#define B_FUSED  0     // 224: fused sp/ab/it rows
#define B_WMLP   224   // 64 : fragment-ordered bf16 mlp_w
#define B_WBITS  288   // 48 : fragment-ordered bf16 bits-weights (192x256, padded)
#define B_MERGED 336   // 421: merged one-hot/boost/action rows
#define B_IDXS   757   // 64 : per-entity packed ridx (16 rows + 6 bitwords)
#define NB_PREP  821

__device__ __forceinline__ unsigned short f2bf(float f) {
    unsigned int u = __float_as_uint(f);
    u += 0x7fffu + ((u >> 16) & 1u);   // round-to-nearest-even
    return (unsigned short)(u >> 16);
}

// single-inst packed f32->bf16 (RTNE): low16 = bf16(lo), high16 = bf16(hi)
__device__ __forceinline__ unsigned int cvt_pk_bf16(float lo, float hi) {
    unsigned int r;
    asm("v_cvt_pk_bf16_f32 %0, %1, %2" : "=v"(r) : "v"(lo), "v"(hi));
    return r;
}

// ---------------------------------------------------------------------------
// K0: all prep
// ---------------------------------------------------------------------------
__global__ __launch_bounds__(1024) void k_prep(
    const float* __restrict__ sp_tbl, const float* __restrict__ ab_tbl,
    const float* __restrict__ it_tbl, const float* __restrict__ sp_emb,
    const float* __restrict__ ab_emb, const float* __restrict__ it_emb,
    const float* __restrict__ act_emb, const float* __restrict__ agg_w,
    const float* __restrict__ agg_b,  const float* __restrict__ mlp_w,
    const int* __restrict__ ent,
    unsigned short* __restrict__ tbl, unsigned short* __restrict__ wfrag,
    unsigned short* __restrict__ wbits, unsigned int* __restrict__ ridx)
{
    __shared__ float rowbuf[4 * 512];
    __shared__ float part[4][4][256];
    int blk = blockIdx.x, t = threadIdx.x, c = t & 255;
#define W(x) agg_w[(size_t)(x) * 256 + c]

    if (blk < B_WMLP) {
        // ---- fused species/ability/item rows: 4 rows/block, K split 4 ways ----
        int r0 = blk << 2;
        const float* src; const float* emb; int len, wbase; bool add_b;
        if (r0 < 512)      { src = sp_tbl + (size_t)r0 * 512;           emb = sp_emb + (size_t)r0 * 256;           len = 512; wbase = 0;   add_b = true;  }
        else if (r0 < 640) { int q = r0 - 512; src = ab_tbl + (size_t)q * 128; emb = ab_emb + (size_t)q * 256; len = 128; wbase = 512; add_b = false; }
        else               { int q = r0 - 640; src = it_tbl + (size_t)q * 256; emb = it_emb + (size_t)q * 256; len = 256; wbase = 640; add_b = false; }
        int tot = len << 2;
        for (int i = t; i < tot; i += 1024) rowbuf[i] = src[i];
        __syncthreads();
        int kq   = t >> 8;
        int len4 = len >> 2;
        int kbeg = kq * len4, kend = kbeg + len4;
        float a0 = 0.f, a1 = 0.f, a2 = 0.f, a3 = 0.f;
        #pragma unroll 4
        for (int k = kbeg; k < kend; ++k) {
            float w = W(wbase + k);
            a0 += rowbuf[k] * w;
            a1 += rowbuf[len + k] * w;
            a2 += rowbuf[2 * len + k] * w;
            a3 += rowbuf[3 * len + k] * w;
        }
        part[0][kq][c] = a0; part[1][kq][c] = a1;
        part[2][kq][c] = a2; part[3][kq][c] = a3;
        __syncthreads();
        int row = t >> 8;
        float s = part[row][0][c] + part[row][1][c] + part[row][2][c] + part[row][3][c]
                + emb[row * 256 + c] + (add_b ? agg_b[c] : 0.f);
        tbl[(size_t)(r0 + row) * 256 + c] = f2bf(s);
        return;
    }
    if (blk < B_WBITS) {
        // ---- fragment-ordered bf16 mlp_w ----
        int idx = ((blk - B_WMLP) << 10) + t;   // 0..65535
        int j   = idx & 7;
        int fl  = (idx >> 3) & 63;
        int k0g = (idx >> 9) & 7;
        int nt  = idx >> 12;
        int k   = k0g * 32 + (fl >> 4) * 8 + j;
        int col = nt * 16 + (fl & 15);
        wfrag[idx] = f2bf(mlp_w[(size_t)k * 256 + col]);
        return;
    }
    if (blk < B_MERGED) {
        // ---- fragment-ordered bf16 bits-weights (rows 1171..1346 of agg_w) ----
        int idx = ((blk - B_WBITS) << 10) + t;  // 0..49151
        int j   = idx & 7;
        int ln  = (idx >> 3) & 63;
        int r2  = idx >> 9;                     // 0..95
        int kt  = r2 % 6;
        int nt  = r2 / 6;
        int k   = kt * 32 + ((ln >> 4) << 3) + j;
        int col = (nt << 4) + (ln & 15);
        float v = (k < 176) ? agg_w[(size_t)(1171 + k) * 256 + col] : 0.f;
        wbits[idx] = f2bf(v);
        return;
    }
    if (blk < B_IDXS) {
        // ---- merged category rows: 4 rows per block ----
        int r = ((blk - B_MERGED) << 2) + (t >> 8);   // 0..1683
        int row; float acc;
        if (r < 404)       { int f3 = r >> 2, f4 = (r >> 1) & 1, f5 = r & 1;
                             acc = W(896 + f3) + W(997 + f4) + W(999 + f5); row = R_T1 + r; }
        else if (r < 532)  { int i = r - 404; int f6 = i >> 2, f11 = (i >> 1) & 1, f12 = i & 1;
                             acc = W(1001 + f6) + (float)f6 * (1.f / 31.f) * W(1347)
                                 + W(1062 + f11) + W(1064 + f12); row = R_T2 + i; }
        else if (r < 556)  { int i = r - 532; acc = W(1033 + (i >> 3)) + W(1036 + (i & 7)); row = R_T3 + i; }
        else if (r < 588)  { int i = r - 556; acc = W(1044 + (i >> 1)) + W(1060 + (i & 1)); row = R_T4 + i; }
        else if (r < 652)  { int i = r - 588; acc = W(1066 + (i >> 3)) + W(1074 + ((i >> 1) & 3)) + W(1078 + (i & 1)); row = R_T5 + i; }
        else if (r < 821)  { int i = r - 652; acc = W(1080 + i / 13) + W(1093 + i % 13); row = R_T6 + i; }
        else if (r < 990)  { int i = r - 821; acc = W(1106 + i / 13) + W(1119 + i % 13); row = R_T7 + i; }
        else if (r < 1159) { int i = r - 990; acc = W(1132 + i / 13) + W(1145 + i % 13); row = R_T8 + i; }
        else if (r < 1172) { int i = r - 1159; acc = W(1158 + i); row = R_T9 + i; }
        else               { int i = r - 1172; acc = act_emb[(size_t)i * 256 + c]; row = R_ACT + i; }
        tbl[(size_t)row * 256 + c] = f2bf(acc);
        return;
    }
    {
        // ---- per-entity packed ridx: 8 row-pairs + 6 bitwords + pad = 64 B ----
        int e = ((blk - B_IDXS) << 10) + t;
        size_t bb = (size_t)e * (NFEAT * 4);
        const uint4* wp = reinterpret_cast<const uint4*>(
            reinterpret_cast<const char*>(ent) + (bb & ~(size_t)15));
        uint4 q0 = wp[0], q1 = wp[1], q2 = wp[2], q3 = wp[3], q4 = wp[4];
        uint4 q5 = wp[5], q6 = wp[6], q7 = wp[7], q8 = wp[8], q9 = wp[9];
        unsigned int v[40] = {q0.x,q0.y,q0.z,q0.w, q1.x,q1.y,q1.z,q1.w,
                              q2.x,q2.y,q2.z,q2.w, q3.x,q3.y,q3.z,q3.w,
                              q4.x,q4.y,q4.z,q4.w, q5.x,q5.y,q5.z,q5.w,
                              q6.x,q6.y,q6.z,q6.w, q7.x,q7.y,q7.z,q7.w,
                              q8.x,q8.y,q8.z,q8.w, q9.x,q9.y,q9.z,q9.w};
        int f[NFEAT];
        if (e & 1) {
            #pragma unroll
            for (int i = 0; i < NFEAT; ++i) f[i] = (int)v[i + 2];
        } else {
            #pragma unroll
            for (int i = 0; i < NFEAT; ++i) f[i] = (int)v[i];
        }
        int rw[16];
        rw[0]  = f[0];
        rw[1]  = R_AB + f[1];
        rw[2]  = R_IT + f[2];
        rw[3]  = R_T1 + f[3] * 4 + f[4] * 2 + f[5];
        rw[4]  = R_T2 + f[6] * 4 + f[11] * 2 + f[12];
        rw[5]  = R_T3 + f[7] * 8 + f[8];
        rw[6]  = R_T4 + f[9] * 2 + f[10];
        rw[7]  = R_T5 + f[13] * 8 + f[14] * 2 + f[15];
        rw[8]  = R_T6 + f[16] * 13 + f[17];
        rw[9]  = R_T7 + f[18] * 13 + f[19];
        rw[10] = R_T8 + f[20] * 13 + f[21];
        rw[11] = R_T9 + f[22];
        rw[12] = R_ACT + f[34];
        rw[13] = R_ACT + f[35];
        rw[14] = R_ACT + f[36];
        rw[15] = R_ACT + f[37];
        unsigned int p[16];
        #pragma unroll
        for (int i = 0; i < 8; ++i)
            p[i] = (unsigned int)rw[2 * i] | ((unsigned int)rw[2 * i + 1] << 16);
        #pragma unroll
        for (int i = 0; i < 5; ++i)
            p[8 + i] = (unsigned int)(f[23 + 2 * i] & 0xffff) | ((unsigned int)f[24 + 2 * i] << 16);
        p[13] = (unsigned int)(f[33] & 0xffff);
        p[14] = 0; p[15] = 0;
        uint4* dst = reinterpret_cast<uint4*>(ridx + (size_t)e * 16);
        dst[0] = make_uint4(p[0], p[1], p[2], p[3]);
        dst[1] = make_uint4(p[4], p[5], p[6], p[7]);
        dst[2] = make_uint4(p[8], p[9], p[10], p[11]);
        dst[3] = make_uint4(p[12], p[13], p[14], p[15]);
    }
#undef W
}

// ---------------------------------------------------------------------------
// K1: fused encode + mlp.  Block = 512 threads (8 waves), 64 entities.
//  A1: wave w encodes entities w*8..w*8+7, TWO entities per iteration:
//      all 16 paired dwordx4 gathers batch-issued before any consumption
//      (one latency exposure per 2 entities; needs ~64 data VGPRs — cap 128
//      via launch_bounds(512,4)).  Index words preloaded to SGPRs.
//      lanes 0-31 even rows / 32-63 odd rows; shfl_xor(32) combine;
//      cvt_pk_bf16 -> xw (XOR-swizzled 16B units).
//  A2: bits via MFMA (A = expanded 0/1 bits, B = wbits frags); in-place RMW
//      x = bf16(relu(f32(x) + D)).
//  B : mlp MFMA (A from xw, B from wfrag), bias + species mask, store.
// ---------------------------------------------------------------------------
__global__ __launch_bounds__(512, 4) void k_fused_em(
    const unsigned int* __restrict__ ridx, const unsigned short* __restrict__ tbl,
    const unsigned short* __restrict__ wfrag, const unsigned short* __restrict__ wbits,
    const float* __restrict__ mlp_b, float* __restrict__ out)
{
    __shared__ unsigned short xw[64 * 256];   // 32,768 B
    __shared__ unsigned int bitw[64 * 6];     // 1,536 B
    __shared__ unsigned char smask[64];
    int t    = threadIdx.x;
    int w    = t >> 6;
    int lane = t & 63;
    int half = lane >> 5;
    int cp   = lane & 31;
    int wu   = __builtin_amdgcn_readfirstlane(w);
    int eb   = blockIdx.x << 6;
    const char* tb = reinterpret_cast<const char*>(tbl);
    char* xb = reinterpret_cast<char*>(xw);

    // stage bitwords + species mask
    if (t < 384) {
        int e = t / 6, k = t - e * 6;
        bitw[t] = ridx[(size_t)(eb + e) * 16 + 8 + k];
    }
    if (t < 64) smask[t] = ((ridx[(size_t)(eb + t) * 16] & 0xffffu) < 2u) ? 1 : 0;

    // ---------------- A1: gather-encode 8 entities -> bf16 in xw ------------
    {
        int cb = cp << 4;
        const unsigned int* rqw = ridx + (size_t)(eb + (wu << 3)) * 16;  // uniform
        // preload all 8 entities' row-index words (SGPRs)
        unsigned int sidx[64];
        #pragma unroll
        for (int i = 0; i < 8; ++i) {
            #pragma unroll
            for (int j = 0; j < 8; ++j) sidx[i * 8 + j] = rqw[(i << 4) + j];
        }
        for (int i = 0; i < 8; i += 2) {
            uint4 va[8], vb[8];
            #pragma unroll
            for (int j = 0; j < 8; ++j) {
                unsigned int pa = sidx[i * 8 + j];
                unsigned int ra = half ? (pa >> 16) : (pa & 0xffffu);
                va[j] = *reinterpret_cast<const uint4*>(tb + ((size_t)ra << 9) + cb);
            }
            #pragma unroll
            for (int j = 0; j < 8; ++j) {
                unsigned int pb = sidx[(i + 1) * 8 + j];
                unsigned int rb = half ? (pb >> 16) : (pb & 0xffffu);
                vb[j] = *reinterpret_cast<const uint4*>(tb + ((size_t)rb << 9) + cb);
            }
            #pragma unroll
            for (int pass = 0; pass < 2; ++pass) {
                uint4* v = pass ? vb : va;
                int el = (wu << 3) + i + pass;
                f32x2 aE0 = (f32x2){0.f, 0.f}, aO0 = (f32x2){0.f, 0.f};
                f32x2 aE1 = (f32x2){0.f, 0.f}, aO1 = (f32x2){0.f, 0.f};
                #pragma unroll
                for (int j = 0; j < 8; ++j) {
                    aE0 += (f32x2){__uint_as_float(v[j].x << 16),         __uint_as_float(v[j].y << 16)};
                    aO0 += (f32x2){__uint_as_float(v[j].x & 0xffff0000u), __uint_as_float(v[j].y & 0xffff0000u)};
                    aE1 += (f32x2){__uint_as_float(v[j].z << 16),         __uint_as_float(v[j].w << 16)};
                    aO1 += (f32x2){__uint_as_float(v[j].z & 0xffff0000u), __uint_as_float(v[j].w & 0xffff0000u)};
                }
                float s0 = aE0[0] + __shfl_xor(aE0[0], 32);
                float s1 = aO0[0] + __shfl_xor(aO0[0], 32);
                float s2 = aE0[1] + __shfl_xor(aE0[1], 32);
                float s3 = aO0[1] + __shfl_xor(aO0[1], 32);
                float s4 = aE1[0] + __shfl_xor(aE1[0], 32);
                float s5 = aO1[0] + __shfl_xor(aO1[0], 32);
                float s6 = aE1[1] + __shfl_xor(aE1[1], 32);
                float s7 = aO1[1] + __shfl_xor(aO1[1], 32);
                if (half == 0) {
                    unsigned int o0 = cvt_pk_bf16(s0, s1);
                    unsigned int o1 = cvt_pk_bf16(s2, s3);
                    unsigned int o2 = cvt_pk_bf16(s4, s5);
                    unsigned int o3 = cvt_pk_bf16(s6, s7);
                    int up = cp ^ (el & 7);
                    *reinterpret_cast<uint4*>(xb + (el << 9) + (up << 4)) = make_uint4(o0, o1, o2, o3);
                }
            }
        }
    }
    __syncthreads();

    // ---------------- A2: bits via MFMA + in-place relu RMW -----------------
    int rc  = lane & 15;
    int kg  = lane >> 4;
    int nt0 = wu << 1;
    int c0  = wu << 5;

    f32x4 D0[4], D1[4];
    #pragma unroll
    for (int mt = 0; mt < 4; ++mt) { D0[mt] = (f32x4){0.f,0.f,0.f,0.f}; D1[mt] = (f32x4){0.f,0.f,0.f,0.f}; }

    #pragma unroll
    for (int kt = 0; kt < 6; ++kt) {
        bf16x8 b0 = *reinterpret_cast<const bf16x8*>(wbits + (((size_t)(nt0 * 6 + kt)) << 9) + (lane << 3));
        bf16x8 b1 = *reinterpret_cast<const bf16x8*>(wbits + (((size_t)((nt0 + 1) * 6 + kt)) << 9) + (lane << 3));
        #pragma unroll
        for (int mt = 0; mt < 4; ++mt) {
            unsigned int wb = bitw[((mt << 4) + rc) * 6 + kt];
            unsigned int bs = wb >> (kg << 3);
            unsigned int e0 = ((bs & 1u)   ? 0x3F80u : 0u) | ((bs & 2u)   ? 0x3F800000u : 0u);
            unsigned int e1 = ((bs & 4u)   ? 0x3F80u : 0u) | ((bs & 8u)   ? 0x3F800000u : 0u);
            unsigned int e2 = ((bs & 16u)  ? 0x3F80u : 0u) | ((bs & 32u)  ? 0x3F800000u : 0u);
            unsigned int e3 = ((bs & 64u)  ? 0x3F80u : 0u) | ((bs & 128u) ? 0x3F800000u : 0u);
            bf16x8 afr = __builtin_bit_cast(bf16x8, (u32x4){e0, e1, e2, e3});
            D0[mt] = __builtin_amdgcn_mfma_f32_16x16x32_bf16(afr, b0, D0[mt], 0, 0, 0);
            D1[mt] = __builtin_amdgcn_mfma_f32_16x16x32_bf16(afr, b1, D1[mt], 0, 0, 0);
        }
    }

    #pragma unroll
    for (int mt = 0; mt < 4; ++mt) {
        #pragma unroll
        for (int j = 0; j < 4; ++j) {
            int row  = (mt << 4) + (kg << 2) + j;
            int colA = c0 + rc;
            int colB = colA + 16;
            int uA = (colA >> 3) ^ (row & 7);
            int uB = (colB >> 3) ^ (row & 7);
            unsigned short* pA = reinterpret_cast<unsigned short*>(
                xb + (row << 9) + (uA << 4) + ((colA & 7) << 1));
            unsigned short* pB = reinterpret_cast<unsigned short*>(
                xb + (row << 9) + (uB << 4) + ((colB & 7) << 1));
            float xA = __uint_as_float((unsigned int)(*pA) << 16) + D0[mt][j];
            float xB = __uint_as_float((unsigned int)(*pB) << 16) + D1[mt][j];
            *pA = (unsigned short)cvt_pk_bf16(fmaxf(xA, 0.f), 0.f);
            *pB = (unsigned short)cvt_pk_bf16(fmaxf(xB, 0.f), 0.f);
        }
    }
    __syncthreads();

    // ---------------- B: mlp MFMA, 64 rows x 32 cols per wave ---------------
    f32x4 acc0[4], acc1[4];
    #pragma unroll
    for (int mt = 0; mt < 4; ++mt) {
        acc0[mt] = (f32x4){0.f,0.f,0.f,0.f};
        acc1[mt] = (f32x4){0.f,0.f,0.f,0.f};
    }

    #pragma unroll
    for (int k0g = 0; k0g < 8; ++k0g) {
        bf16x8 b0 = *reinterpret_cast<const bf16x8*>(
            wfrag + (((size_t)(nt0 * 8 + k0g)) << 9) + (lane << 3));
        bf16x8 b1 = *reinterpret_cast<const bf16x8*>(
            wfrag + (((size_t)((nt0 + 1) * 8 + k0g)) << 9) + (lane << 3));
        int up = ((k0g << 2) + kg) ^ (rc & 7);
        #pragma unroll
        for (int mt = 0; mt < 4; ++mt) {
            int r = (mt << 4) + rc;
            bf16x8 a = *reinterpret_cast<const bf16x8*>(xb + (r << 9) + (up << 4));
            acc0[mt] = __builtin_amdgcn_mfma_f32_16x16x32_bf16(a, b0, acc0[mt], 0, 0, 0);
            acc1[mt] = __builtin_amdgcn_mfma_f32_16x16x32_bf16(a, b1, acc1[mt], 0, 0, 0);
        }
    }

    float bias0 = mlp_b[c0 + rc];
    float bias1 = mlp_b[c0 + 16 + rc];
    #pragma unroll
    for (int mt = 0; mt < 4; ++mt) {
        unsigned int mw = *reinterpret_cast<const unsigned int*>(&smask[(mt << 4) + (kg << 2)]);
        #pragma unroll
        for (int j = 0; j < 4; ++j) {
            int row = eb + (mt << 4) + (kg << 2) + j;
            bool m = (mw >> (8 * j)) & 1u;
            out[(size_t)row * 256 + c0 + rc]      = m ? 0.f : (acc0[mt][j] + bias0);
            out[(size_t)row * 256 + c0 + 16 + rc] = m ? 0.f : (acc1[mt][j] + bias1);
        }
    }
}

// ---------------------------------------------------------------------------
extern "C" void kernel_launch(void* const* d_in, const int* in_sizes, int n_in,
                              void* d_out, int out_size, void* d_ws, size_t ws_size,
                              hipStream_t stream)
{
    const int*   ent     = (const int*)d_in[0];
    const float* sp_tbl  = (const float*)d_in[1];
    const float* ab_tbl  = (const float*)d_in[2];
    const float* it_tbl  = (const float*)d_in[3];
    const float* sp_emb  = (const float*)d_in[4];
    const float* ab_emb  = (const float*)d_in[5];
    const float* it_emb  = (const float*)d_in[6];
    const float* act_emb = (const float*)d_in[7];
    const float* agg_w   = (const float*)d_in[8];
    const float* agg_b   = (const float*)d_in[9];
    const float* mlp_w   = (const float*)d_in[10];
    const float* mlp_b   = (const float*)d_in[11];
    float* out = (float*)d_out;

    char* ws = (char*)d_ws;
    unsigned short* tbl   = (unsigned short*)(ws);               // 2580*512   = 1,320,960 B
    unsigned short* wfrag = (unsigned short*)(ws + 1320960);     //   131,072 B
    unsigned short* wbits = (unsigned short*)(ws + 1452032);     //    98,304 B
    unsigned int*   ridx  = (unsigned int*)  (ws + 1550336);     // 65536*64   = 4,194,304 B

    k_prep    <<<dim3(NB_PREP), dim3(1024), 0, stream>>>(sp_tbl, ab_tbl, it_tbl,
                                                         sp_emb, ab_emb, it_emb,
                                                         act_emb, agg_w, agg_b, mlp_w,
                                                         ent, tbl, wfrag, wbits, ridx);
    k_fused_em<<<dim3(1024),    dim3(512),  0, stream>>>(ridx, tbl, wfrag, wbits, mlp_b, out);
}